// Round 3
// baseline (435.213 us; speedup 1.0000x reference)
//
#include <hip/hip_runtime.h>
#include <math.h>

#define PI2f 6.28318530717958647692f

// B=16, Ci=Co=64, H=W=256, M1=M2=16. Modes j=0..31, freq f=(j<16)?j:j-32.
//
// ALL scratch lives inside d_out (67,108,864 floats = 1024 regions x 65536):
//   Ft slice for bo : R(bo) + [0, 2048)      (mix_k -> inv_fused)
//   X  slice for bi : R(bi) + [2048, 3072)   (fwdH -> mix_k)
//   Wt[m], m<512    : R(m)  + [4096, 12288)  (wtrans -> mix_k)
//   A  slice for bi : R(bi) + [16384, 24576) (fwdW -> fwdH)
// inv_fused block bo stages its own Ft to LDS BEFORE overwriting its region.

static constexpr size_t REG = 65536;

// ---------------- weights -> mode-major, coalesced writes ----------------
// block = one m (grid 512). dst: Wt[m][io] contiguous; src gathered (L2/L3-cached)
__global__ __launch_bounds__(256) void wtrans(const float* __restrict__ w1,
                                              const float* __restrict__ w2,
                                              float* g) {
    const int m = blockIdx.x;                   // 0..511, m = j*16+k
    const int j = m >> 4, k = m & 15, xm = j & 15;
    const float2* s2 = (const float2*)((j < 16) ? w1 : w2);
    float* dst = g + (size_t)m * REG + 4096;
    const int t = threadIdx.x;
#pragma unroll
    for (int q = 0; q < 16; q++) {
        int io = q * 256 + t;                   // 0..4095
        float2 v = s2[(size_t)io * 256 + xm * 16 + k];
        *(float2*)(dst + (size_t)io * 2) = v;   // coalesced
    }
}

// ---------------- stage 1: A[row][k] = sum_w x[row][w] e^{-2pi i k w/256} ----------------
// grid 1024: block bi owns rows of image bi. LDS twiddle table, no global tw loads.
__global__ __launch_bounds__(256) void fwdW(const float* __restrict__ x,
                                            float* g) {
    __shared__ float tws[8192];                 // [w][k][2] = e^{-2pi i wk/256}, 32 KB
    __shared__ float xs[256 * 17];              // 256 rows x 16-col chunk, pad 17
    const int t = threadIdx.x;
    const int bi = blockIdx.x;
    const float* xim = x + (size_t)bi * 65536;

    // build table: idx = w*16+k
#pragma unroll
    for (int q = 0; q < 16; q++) {
        int idx = q * 256 + t;
        int w = idx >> 4, k = idx & 15;
        int r = (w * k) & 255;                  // exact arg reduction
        float s, c;
        sincosf(PI2f * (float)r / 256.0f, &s, &c);
        tws[idx * 2]     = c;
        tws[idx * 2 + 1] = -s;
    }

    float ar[16], ai[16];
#pragma unroll
    for (int k = 0; k < 16; k++) { ar[k] = 0.f; ai[k] = 0.f; }

    const int sr = t >> 2, sc = (t & 3) * 4;    // staging: 4 lanes per row
    for (int cc = 0; cc < 16; cc++) {
        const int w0 = cc * 16;
        __syncthreads();                        // covers table build (cc=0) + prev reads
#pragma unroll
        for (int q = 0; q < 4; q++) {
            int rr = q * 64 + sr;
            float4 v = *(const float4*)(xim + (size_t)rr * 256 + w0 + sc);
            xs[rr * 17 + sc + 0] = v.x;
            xs[rr * 17 + sc + 1] = v.y;
            xs[rr * 17 + sc + 2] = v.z;
            xs[rr * 17 + sc + 3] = v.w;
        }
        __syncthreads();
        const float* xr = xs + t * 17;          // thread t owns row h=t
#pragma unroll 4
        for (int w = 0; w < 16; w++) {
            float xv = xr[w];
            const float4* tp = (const float4*)(tws + (size_t)(w0 + w) * 32);
#pragma unroll
            for (int q = 0; q < 8; q++) {       // q covers k=2q,2q+1
                float4 tv = tp[q];              // broadcast ds_read_b128
                ar[2 * q]     = fmaf(xv, tv.x, ar[2 * q]);
                ai[2 * q]     = fmaf(xv, tv.y, ai[2 * q]);
                ar[2 * q + 1] = fmaf(xv, tv.z, ar[2 * q + 1]);
                ai[2 * q + 1] = fmaf(xv, tv.w, ai[2 * q + 1]);
            }
        }
    }
    float* Ap = g + (size_t)bi * REG + 16384 + (size_t)t * 32;
#pragma unroll
    for (int k = 0; k < 8; k++) {
        *(float4*)(Ap + 4 * k) = make_float4(ar[2 * k], ai[2 * k], ar[2 * k + 1], ai[2 * k + 1]);
    }
}

// ---------------- stage 2: X[bi][j][k] = sum_h A[bi][h][k] e^{-2pi i f(j) h/256} ----------------
__global__ __launch_bounds__(256) void fwdH(float* g) {
    __shared__ float As[8192];                  // 32 KB
    const int bi = blockIdx.x;
    const int t = threadIdx.x;
    const float* Ap = g + (size_t)bi * REG + 16384;
#pragma unroll
    for (int q = 0; q < 8; q++) {
        *(float4*)(As + (q * 256 + t) * 4) = *(const float4*)(Ap + (q * 256 + t) * 4);
    }
    __syncthreads();

    const int k = t & 15, jb = t >> 4;
    float* Xp = g + (size_t)bi * REG + 2048;
    for (int half = 0; half < 2; half++) {
        int j = jb + half * 16;
        int f = (j < 16) ? j : j - 32;
        float s, c;
        sincosf(-PI2f * (float)f / 256.0f, &s, &c);
        float er = 1.f, ei = 0.f, accr = 0.f, acci = 0.f;
        for (int h = 0; h < 256; h++) {
            float2 a = *(const float2*)(As + (h * 16 + k) * 2);
            accr = fmaf(a.x, er, fmaf(-a.y, ei, accr));
            acci = fmaf(a.x, ei, fmaf( a.y, er, acci));
            float nr = er * c - ei * s;
            ei = fmaf(er, s, ei * c);
            er = nr;
        }
        *(float2*)(Xp + (j * 16 + k) * 2) = make_float2(accr, acci);
    }
}

// ---------------- stage 3: Ft[b][m][o] = sum_i X[b][i][m] * Wt[m][i][o] ----------------
__global__ __launch_bounds__(256) void mix_k(float* g) {
    const int wave = threadIdx.x >> 6, lane = threadIdx.x & 63;
    const int task = blockIdx.x * 4 + wave;     // 0..8191
    const int b = task >> 9, m = task & 511;
    const float* Xb = g + 2048 + (size_t)(b * 64) * REG + (size_t)m * 2;  // +i*REG, lane-uniform
    const float* Wp = g + (size_t)m * REG + 4096 + (size_t)lane * 2;      // +i*128
    float accr = 0.f, acci = 0.f;
    for (int i = 0; i < 64; i++) {
        float xr = Xb[(size_t)i * REG], xi = Xb[(size_t)i * REG + 1];
        float wr = Wp[i * 128],          wi = Wp[i * 128 + 1];
        accr = fmaf(xr, wr, fmaf(-xi, wi, accr));
        acci = fmaf(xr, wi, fmaf( xi, wr, acci));
    }
    float* Fp = g + (size_t)(b * 64 + lane) * REG + (size_t)m * 2;
    Fp[0] = accr;
    Fp[1] = acci;
}

// ---------------- inverse: H-iDFT + irfft-W with Hermitian pairing ----------------
// block = one bo region. Thread t owns output row h=t.
__global__ __launch_bounds__(256) void inv_fused(float* g) {
    __shared__ float Fs[2048];                  // Ft slice, 8 KB
    __shared__ float tw2[129 * 32];             // [m][k][2]=(wt*cos, wt*sin), 16.5 KB
    __shared__ float T[256 * 17];               // transpose tile, 17 KB
    const int t = threadIdx.x;
    const int bo = blockIdx.x;
    float* regn = g + (size_t)bo * REG;

    // stage own Ft slice BEFORE any output write
#pragma unroll
    for (int q = 0; q < 4; q++) {
        int idx = q * 256 + t;
        float2 v = *(const float2*)(regn + (size_t)idx * 2);
        *(float2*)(Fs + idx * 2) = v;
    }
    // build weighted table: wt = (k==0 ? 1 : 2)/65536
#pragma unroll
    for (int q = 0; q < 9; q++) {
        int idx = q * 256 + t;
        if (idx < 129 * 16) {
            int m = idx >> 4, k = idx & 15;
            int r = (m * k) & 255;
            float s, c;
            sincosf(PI2f * (float)r / 256.0f, &s, &c);
            float wt = ((k == 0) ? 1.0f : 2.0f) / 65536.0f;
            tw2[idx * 2]     = c * wt;
            tw2[idx * 2 + 1] = s * wt;
        }
    }
    __syncthreads();

    // phase 1: Y[h=t][k] = sum_f Ft[j(f)][k] e^{+2pi i f t/256}
    float Yr[16], Yi[16];
#pragma unroll
    for (int k = 0; k < 16; k++) { Yr[k] = 0.f; Yi[k] = 0.f; }
    float rs, rc;
    sincosf(PI2f * (float)t / 256.0f, &rs, &rc);        // ratio e^{+2pi i t/256}
    float es, ec;
    sincosf(-PI2f * (float)(t & 15) / 16.0f, &es, &ec); // e^{-2pi i 16 t/256}
    float er = ec, ei = es;
    for (int sdx = 0; sdx < 32; sdx++) {                // f = sdx-16
        int j = (sdx < 16) ? sdx + 16 : sdx - 16;
        const float* fj = Fs + j * 32;
#pragma unroll
        for (int k = 0; k < 16; k++) {
            float fr = fj[2 * k], fi = fj[2 * k + 1];
            Yr[k] = fmaf(fr, er, fmaf(-fi, ei, Yr[k]));
            Yi[k] = fmaf(fr, ei, fmaf( fi, er, Yi[k]));
        }
        float nr = er * rc - ei * rs;
        ei = fmaf(er, rs, ei * rc);
        er = nr;
    }

    // phase 2: P_m = sum Yr*c, Q_m = sum Yi*s; out[m]=P-Q, out[256-m]=P+Q
    for (int cc = 0; cc < 16; cc++) {
        float lo[8], hi[8];
#pragma unroll
        for (int i = 0; i < 8; i++) {
            int m = cc * 8 + i;
            const float4* tp = (const float4*)(tw2 + m * 32);
            float P = 0.f, Q = 0.f;
#pragma unroll
            for (int q = 0; q < 8; q++) {       // k = 2q, 2q+1
                float4 tv = tp[q];              // broadcast
                P = fmaf(Yr[2 * q], tv.x, P);
                Q = fmaf(Yi[2 * q], tv.y, Q);
                P = fmaf(Yr[2 * q + 1], tv.z, P);
                Q = fmaf(Yi[2 * q + 1], tv.w, Q);
            }
            lo[i] = P - Q;
            hi[i] = P + Q;
        }
        if (cc == 0) {                          // slot hi[0] carries col 128 (m=128, s=0)
            const float4* tp = (const float4*)(tw2 + 128 * 32);
            float P = 0.f;
#pragma unroll
            for (int q = 0; q < 8; q++) {
                float4 tv = tp[q];
                P = fmaf(Yr[2 * q], tv.x, P);
                P = fmaf(Yr[2 * q + 1], tv.z, P);
            }
            hi[0] = P;
        }
        __syncthreads();
#pragma unroll
        for (int i = 0; i < 8; i++) { T[t * 17 + i] = lo[i]; T[t * 17 + 8 + i] = hi[i]; }
        __syncthreads();
        // coalesced-ish store: lane covers (colj = t&15, rows rb, rb+16, ...)
        const int colj = t & 15, rb = t >> 4;
        int gcol;
        if (colj < 8)                gcol = cc * 8 + colj;
        else if (cc == 0 && colj == 8) gcol = 128;
        else                         gcol = 256 - (cc * 8 + (colj - 8));
#pragma unroll
        for (int it = 0; it < 16; it++) {
            int row = it * 16 + rb;
            regn[(size_t)row * 256 + gcol] = T[row * 17 + colj];
        }
    }
}

extern "C" void kernel_launch(void* const* d_in, const int* in_sizes, int n_in,
                              void* d_out, int out_size, void* d_ws, size_t ws_size,
                              hipStream_t stream) {
    const float* x  = (const float*)d_in[0];
    const float* w1 = (const float*)d_in[1];
    const float* w2 = (const float*)d_in[2];
    float* g = (float*)d_out;
    (void)d_ws; (void)ws_size;

    wtrans   <<<512,  256, 0, stream>>>(w1, w2, g);
    fwdW     <<<1024, 256, 0, stream>>>(x, g);
    fwdH     <<<1024, 256, 0, stream>>>(g);
    mix_k    <<<2048, 256, 0, stream>>>(g);
    inv_fused<<<1024, 256, 0, stream>>>(g);
}